// Round 20
// baseline (196.880 us; speedup 1.0000x reference)
//
#include <hip/hip_runtime.h>
#include <math.h>

#define NEG_SLOPE 0.2f
#define BSH 7              // 128 nodes per bucket
#define NBLK_PART 256      // partition blocks

typedef __attribute__((ext_vector_type(8))) short bf16x8;
typedef __attribute__((ext_vector_type(4))) float f32x4;
typedef __attribute__((ext_vector_type(2))) float f32x2;
typedef __attribute__((ext_vector_type(8))) unsigned short ushort8;
typedef __attribute__((ext_vector_type(4))) unsigned short ushort4v;

__device__ __forceinline__ float b2f(unsigned short u){
  return __uint_as_float(((unsigned)u) << 16);
}
__device__ __forceinline__ unsigned short f2b(float f){
  unsigned u = __float_as_uint(f);
  return (unsigned short)((u + 0x7FFFu + ((u >> 16) & 1u)) >> 16);
}

// ---- fp8 e4m3fn helpers (hardware cvt if available, bit-twiddle fallback) ----
#if __has_builtin(__builtin_amdgcn_cvt_pk_f32_fp8) && __has_builtin(__builtin_amdgcn_cvt_pk_fp8_f32)
#define HW_FP8 1
#else
#define HW_FP8 0
#endif

#if !HW_FP8
__device__ __forceinline__ unsigned enc8_one(float f){
  unsigned bits = __float_as_uint(f);
  unsigned s = bits >> 31;
  unsigned e = (bits >> 23) & 255;
  unsigned mant = bits & 0x7FFFFF;
  if(e < 121){
    float af = fabsf(f);
    int m = (int)(af * 512.f + 0.5f);
    if(m > 7) m = 7;
    return (s << 7) | (unsigned)m;
  }
  unsigned lsb = (mant >> 20) & 1;
  mant += 0x7FFFF + lsb;
  if(mant >> 23){ e += 1; mant = 0; }
  unsigned m3 = mant >> 20;
  unsigned e8 = e - 120;
  if(e8 > 15 || (e8 == 15 && m3 == 7)) return (s << 7) | 0x7E;
  return (s << 7) | (e8 << 3) | m3;
}
#endif

template<bool HI>
__device__ __forceinline__ unsigned enc8_pair(float a, float b, unsigned old){
#if HW_FP8
  return __builtin_amdgcn_cvt_pk_fp8_f32(a, b, old, HI);  // HI literal (op_sel)
#else
  unsigned p = enc8_one(a) | (enc8_one(b) << 8);
  return HI ? ((old & 0x0000FFFFu) | (p << 16)) : ((old & 0xFFFF0000u) | p);
#endif
}

__device__ __forceinline__ void dec8x4v(unsigned q, f32x2& lo, f32x2& hi){
#if HW_FP8
  lo = __builtin_amdgcn_cvt_pk_f32_fp8(q, false);
  hi = __builtin_amdgcn_cvt_pk_f32_fp8(q, true);
#else
  auto dec1 = [](unsigned b)->float{
    unsigned s = (b >> 7) & 1, e = (b >> 3) & 15, m = b & 7;
    float v = (e == 0) ? (float)m * 0.001953125f
                       : __uint_as_float(((e + 120) << 23) | (m << 20));
    return s ? -v : v;
  };
  lo[0] = dec1(q & 255); lo[1] = dec1((q >> 8) & 255);
  hi[0] = dec1((q >> 16) & 255); hi[1] = dec1(q >> 24);
#endif
}

// ================= bucket-partitioned CSR build =================
extern "C" __global__ void k_part1(const int* __restrict__ dsts, int E, int N,
                                   int NBUCK, int* __restrict__ bcnt,
                                   int* __restrict__ blockbase){
  __shared__ int hist[512];
  int blk = blockIdx.x, tid = threadIdx.x;
  for(int b = tid; b < NBUCK; b += 256) hist[b] = 0;
  __syncthreads();
  int ET = E + N;
  int chunk = (ET + NBLK_PART - 1)/NBLK_PART;
  int s0 = blk*chunk, s1 = s0+chunk < ET ? s0+chunk : ET;
  for(int e = s0+tid; e < s1; e += 256){
    int d = (e < E) ? dsts[e] : e - E;
    atomicAdd(&hist[d >> BSH], 1);
  }
  __syncthreads();
  for(int b = tid; b < NBUCK; b += 256)
    blockbase[(size_t)blk*NBUCK + b] = atomicAdd(&bcnt[b], hist[b]);
}

extern "C" __global__ void k_bscan(const int* __restrict__ bcnt, int* __restrict__ boffs,
                                   int* __restrict__ offs_last, int NBUCK, int ET){
  __shared__ int sc[512], orig[512];
  int t = threadIdx.x;
  int v = (t < NBUCK) ? bcnt[t] : 0;
  sc[t] = v; orig[t] = v;
  __syncthreads();
  for(int st=1; st<512; st<<=1){
    int u = (t >= st) ? sc[t-st] : 0;
    __syncthreads();
    sc[t] += u;
    __syncthreads();
  }
  if(t < NBUCK) boffs[t] = sc[t] - orig[t];
  if(t == 0){ boffs[NBUCK] = ET; *offs_last = ET; }
}

extern "C" __global__ void k_part2(const int* __restrict__ srcs, const int* __restrict__ dsts,
                                   int E, int N, int NBUCK,
                                   const int* __restrict__ boffs, const int* __restrict__ blockbase,
                                   uint2* __restrict__ pairs){
  __shared__ int cur[512];
  int blk = blockIdx.x, tid = threadIdx.x;
  for(int b = tid; b < NBUCK; b += 256)
    cur[b] = boffs[b] + blockbase[(size_t)blk*NBUCK + b];
  __syncthreads();
  int ET = E + N;
  int chunk = (ET + NBLK_PART - 1)/NBLK_PART;
  int s0 = blk*chunk, s1 = s0+chunk < ET ? s0+chunk : ET;
  for(int e = s0+tid; e < s1; e += 256){
    int s, d;
    if(e < E){ s = srcs[e]; d = dsts[e]; } else { s = d = e - E; }
    int pos = atomicAdd(&cur[d >> BSH], 1);
    uint2 pr; pr.x = (unsigned)d; pr.y = (unsigned)s;
    pairs[pos] = pr;
  }
}

extern "C" __global__ void k_bcsr(const uint2* __restrict__ pairs, const int* __restrict__ boffs,
                                  int N, int* __restrict__ offs, int* __restrict__ csr){
  __shared__ int hist[128], sc[128], lcur[128];
  int b = blockIdx.x, tid = threadIdx.x;
  int node0 = b << BSH;
  int base = boffs[b], endp = boffs[b+1];
  if(tid < 128) hist[tid] = 0;
  __syncthreads();
  for(int i = base + tid; i < endp; i += 256)
    atomicAdd(&hist[pairs[i].x & 127], 1);
  __syncthreads();
  if(tid < 128) sc[tid] = hist[tid];
  __syncthreads();
  for(int st=1; st<128; st<<=1){
    int u = (tid < 128 && tid >= st) ? sc[tid-st] : 0;
    __syncthreads();
    if(tid < 128) sc[tid] += u;
    __syncthreads();
  }
  if(tid < 128){
    int ex = sc[tid] - hist[tid];
    lcur[tid] = ex;
    int n = node0 + tid;
    if(n < N) offs[n] = base + ex;
  }
  __syncthreads();
  for(int i = base + tid; i < endp; i += 256){
    uint2 pr = pairs[i];
    int pos = atomicAdd(&lcur[pr.x & 127], 1);
    csr[base + pos] = (int)pr.y;
  }
}

// ---------------- weight transpose+concat (both layers, one launch) ----------------
extern "C" __global__ void k_wt2(const float* __restrict__ W0, const float* __restrict__ Wr0,
                                 const float* __restrict__ W1, const float* __restrict__ Wr1,
                                 unsigned short* __restrict__ WT0, unsigned short* __restrict__ WT1){
  int idx = blockIdx.x*256 + threadIdx.x;
  const int tot0 = 512*256;
  if(idx < tot0){
    int n = idx >> 8, k = idx & 255;
    const float* W = (n < 256) ? W0 : Wr0;
    int c = (n < 256) ? n : n - 256;
    WT0[idx] = f2b(W[(size_t)k*256 + c]);
  } else {
    idx -= tot0;
    if(idx >= 128*256) return;
    int n = idx >> 8, k = idx & 255;
    const float* W = (n < 64) ? W1 : Wr1;
    int c = (n < 64) ? n : n - 64;
    WT1[idx] = f2b(W[(size_t)k*64 + c]);
  }
}

// ---------------- bf16 MFMA GEMM: A reg-staged->LDS, B direct-to-regs (L2-hot) ----------------
// Barriers drain LDS only (no global_load_lds). Epilogue restaged in 2 half-tiles,
// stride 136 (16B-aligned, bank-skewed).
// mode 0 (layer0): col_blk 0,1 -> fp8 h0q + fused als/ald; col_blk 2,3 -> bf16 r0b.
// mode 1 (layer1): bf16 C (ldc=128) + fp8 g1q (cols<64) + fused als1/ald1.
__launch_bounds__(256)
extern "C" __global__ void k_mgemm(const unsigned short* __restrict__ Ab,
                                   const float* __restrict__ Afp,
                                   const unsigned short* __restrict__ WT,
                                   unsigned short* __restrict__ C, int M,
                                   int MB, int NCB, int mode,
                                   unsigned char* __restrict__ qout,
                                   unsigned short* __restrict__ rout,
                                   const float* __restrict__ asv, const float* __restrict__ adv,
                                   float* __restrict__ alsout, float* __restrict__ aldout){
  int id = blockIdx.x;
  int row_blk, col_blk;
  if(NCB == 4){
    col_blk = (id >> 3) & 3;
    row_blk = (id >> 5)*8 + (id & 7);
  } else {
    row_blk = id; col_blk = 0;
  }
  if(row_blk >= MB) return;

  __shared__ unsigned short SH[64*136];   // 17408B: As (128x64=8192) / CT (64x136=8704)
  unsigned short* As = SH;
  int t = threadIdx.x;
  int lane = t & 63, wid = t >> 6;
  int wr = wid >> 1, wc = wid & 1;
  int row0 = row_blk*128, col0 = col_blk*128;
  f32x4 acc[4][4] = {};

  // A prefetch state (regs)
  float4 va0[4], va1[4];
  bf16x8 au[4];
  const float* afp_ptr[4];
  const unsigned short* ab_ptr[4];
  #pragma unroll
  for(int i=0; i<4; i++){
    int t2 = i*256 + t;
    int r = t2 >> 3, dslot = (t2 & 7) ^ (r & 7);
    int gr = row0 + r; if(gr >= M) gr = M - 1;
    if(Afp){
      afp_ptr[i] = Afp + (size_t)gr*256 + dslot*8;
      va0[i] = *(const float4*)afp_ptr[i];
      va1[i] = *(const float4*)(afp_ptr[i] + 4);
    } else {
      ab_ptr[i] = Ab + (size_t)gr*256 + dslot*8;
      au[i] = *(const bf16x8*)ab_ptr[i];
    }
  }
  // B prefetch (direct to MFMA regs; kb = kc*4 + (lane>>4))
  bf16x8 bcur[4], bnxt[4];
  const unsigned short* bptr[4];
  #pragma unroll
  for(int f=0; f<4; f++){
    int br = wc*64 + f*16 + (lane & 15);
    bptr[f] = WT + (size_t)(col0 + br)*256 + (lane >> 4)*8;
    bcur[f] = *(const bf16x8*)bptr[f];
  }

  for(int k0 = 0; k0 < 256; k0 += 64){
    // staged A regs -> LDS (bf16)
    if(Afp){
      #pragma unroll
      for(int i=0; i<4; i++){
        ushort8 o;
        o[0]=f2b(va0[i].x); o[1]=f2b(va0[i].y); o[2]=f2b(va0[i].z); o[3]=f2b(va0[i].w);
        o[4]=f2b(va1[i].x); o[5]=f2b(va1[i].y); o[6]=f2b(va1[i].z); o[7]=f2b(va1[i].w);
        *(ushort8*)(As + i*2048 + t*8) = o;
      }
    } else {
      #pragma unroll
      for(int i=0; i<4; i++)
        *(bf16x8*)(As + i*2048 + t*8) = au[i];
    }
    __syncthreads();
    // prefetch next A (consumed next iteration)
    if(k0 < 192){
      if(Afp){
        #pragma unroll
        for(int i=0; i<4; i++){
          va0[i] = *(const float4*)(afp_ptr[i] + k0 + 64);
          va1[i] = *(const float4*)(afp_ptr[i] + k0 + 68);
        }
      } else {
        #pragma unroll
        for(int i=0; i<4; i++)
          au[i] = *(const bf16x8*)(ab_ptr[i] + k0 + 64);
      }
    }
    // prefetch B for kc=1
    #pragma unroll
    for(int f=0; f<4; f++) bnxt[f] = *(const bf16x8*)(bptr[f] + k0 + 32);
    // kc = 0
    {
      bf16x8 a[4]; int kb = lane >> 4;
      #pragma unroll
      for(int f=0; f<4; f++){
        int ar = wr*64 + f*16 + (lane & 15);
        a[f] = *(const bf16x8*)&As[ar*64 + ((kb ^ (ar & 7))*8)];
      }
      #pragma unroll
      for(int fm=0; fm<4; fm++)
        #pragma unroll
        for(int fn=0; fn<4; fn++)
          acc[fm][fn] = __builtin_amdgcn_mfma_f32_16x16x32_bf16(a[fm], bcur[fn], acc[fm][fn], 0, 0, 0);
    }
    // prefetch B for next k-step kc=0
    if(k0 < 192){
      #pragma unroll
      for(int f=0; f<4; f++) bcur[f] = *(const bf16x8*)(bptr[f] + k0 + 64);
    }
    // kc = 1
    {
      bf16x8 a[4]; int kb = 4 + (lane >> 4);
      #pragma unroll
      for(int f=0; f<4; f++){
        int ar = wr*64 + f*16 + (lane & 15);
        a[f] = *(const bf16x8*)&As[ar*64 + ((kb ^ (ar & 7))*8)];
      }
      #pragma unroll
      for(int fm=0; fm<4; fm++)
        #pragma unroll
        for(int fn=0; fn<4; fn++)
          acc[fm][fn] = __builtin_amdgcn_mfma_f32_16x16x32_bf16(a[fm], bnxt[fn], acc[fm][fn], 0, 0, 0);
    }
    __syncthreads();
  }

  // ---- epilogue: 2 half-tiles of 64 rows through LDS (stride 136), coalesced output ----
  unsigned short* CT = SH;
  int cg = t & 15;
  #pragma unroll
  for(int half=0; half<2; half++){
    __syncthreads();
    if(wr == half){
      #pragma unroll
      for(int fm=0; fm<4; fm++){
        int rbase = fm*16 + ((lane>>4)<<2);
        #pragma unroll
        for(int r=0; r<4; r++)
          #pragma unroll
          for(int fn=0; fn<4; fn++)
            CT[(rbase+r)*136 + wc*64 + (lane&15) + fn*16] = f2b(acc[fm][fn][r]);
      }
    }
    __syncthreads();
    if(mode == 0){
      bool attn = col_blk < 2;
      int colbase = col0 + cg*8;
      float4 as_lo, as_hi, ad_lo, ad_hi;
      if(attn){
        as_lo = *(const float4*)(asv + colbase);
        as_hi = *(const float4*)(asv + colbase + 4);
        ad_lo = *(const float4*)(adv + colbase);
        ad_hi = *(const float4*)(adv + colbase + 4);
      }
      #pragma unroll
      for(int it=0; it<4; it++){
        int rl = it*16 + (t>>4);
        int row = row0 + half*64 + rl;
        ushort8 vr = *(ushort8*)&CT[rl*136 + cg*8];
        if(attn){
          float f0=b2f(vr[0]),f1=b2f(vr[1]),f2=b2f(vr[2]),f3=b2f(vr[3]);
          float f4=b2f(vr[4]),f5=b2f(vr[5]),f6=b2f(vr[6]),f7=b2f(vr[7]);
          float sd = f0*as_lo.x+f1*as_lo.y+f2*as_lo.z+f3*as_lo.w
                   + f4*as_hi.x+f5*as_hi.y+f6*as_hi.z+f7*as_hi.w;
          float dd = f0*ad_lo.x+f1*ad_lo.y+f2*ad_lo.z+f3*ad_lo.w
                   + f4*ad_hi.x+f5*ad_hi.y+f6*ad_hi.z+f7*ad_hi.w;
          sd += __shfl_xor(sd,1); sd += __shfl_xor(sd,2);   // 4 lanes = 32 cols = 1 head
          dd += __shfl_xor(dd,1); dd += __shfl_xor(dd,2);
          uint2 q;
          q.x = enc8_pair<false>(f0,f1,0u); q.x = enc8_pair<true>(f2,f3,q.x);
          q.y = enc8_pair<false>(f4,f5,0u); q.y = enc8_pair<true>(f6,f7,q.y);
          if(row < M){
            *(uint2*)(qout + (size_t)row*256 + colbase) = q;
            if((t&3)==0){
              int head = colbase >> 5;
              alsout[row*8 + head] = sd;
              aldout[row*8 + head] = dd;
            }
          }
        } else {
          if(row < M)
            *(ushort8*)(rout + (size_t)row*256 + (colbase - 256)) = vr;
        }
      }
    } else {
      #pragma unroll
      for(int it=0; it<4; it++){
        int rl = it*16 + (t>>4);
        int row = row0 + half*64 + rl;
        ushort8 vr = *(ushort8*)&CT[rl*136 + cg*8];
        if(row < M){
          *(ushort8*)(C + (size_t)row*128 + cg*8) = vr;
          if(cg < 8){
            float f0=b2f(vr[0]),f1=b2f(vr[1]),f2=b2f(vr[2]),f3=b2f(vr[3]);
            float f4=b2f(vr[4]),f5=b2f(vr[5]),f6=b2f(vr[6]),f7=b2f(vr[7]);
            uint2 q;
            q.x = enc8_pair<false>(f0,f1,0u); q.x = enc8_pair<true>(f2,f3,q.x);
            q.y = enc8_pair<false>(f4,f5,0u); q.y = enc8_pair<true>(f6,f7,q.y);
            *(uint2*)(qout + (size_t)row*64 + cg*8) = q;
            // fused layer1 logits: dot over 64 g1 cols (8 per lane, reduce over cg 0..7)
            float sd = f0*asv[cg*8+0]+f1*asv[cg*8+1]+f2*asv[cg*8+2]+f3*asv[cg*8+3]
                     + f4*asv[cg*8+4]+f5*asv[cg*8+5]+f6*asv[cg*8+6]+f7*asv[cg*8+7];
            float dd = f0*adv[cg*8+0]+f1*adv[cg*8+1]+f2*adv[cg*8+2]+f3*adv[cg*8+3]
                     + f4*adv[cg*8+4]+f5*adv[cg*8+5]+f6*adv[cg*8+6]+f7*adv[cg*8+7];
            sd += __shfl_xor(sd,1); sd += __shfl_xor(sd,2); sd += __shfl_xor(sd,4);
            dd += __shfl_xor(dd,1); dd += __shfl_xor(dd,2); dd += __shfl_xor(dd,4);
            if((t&15)==0){
              alsout[row] = sd;
              aldout[row] = dd;
            }
          }
        }
      }
    }
  }
}

// ---- gather layer0: WAVE-per-node, zero LDS / zero barriers ----
__launch_bounds__(256)
extern "C" __global__ void k_gather0(const unsigned short* __restrict__ r0b,
                                     const unsigned char* __restrict__ h0q,
                                     const float* __restrict__ als0, const float* __restrict__ ald0,
                                     const int* __restrict__ offs, const int* __restrict__ csr,
                                     const float* __restrict__ b0, const float* __restrict__ br0,
                                     unsigned short* __restrict__ h1b, int N){
  int n = blockIdx.x*4 + (threadIdx.x >> 6);
  if(n >= N) return;
  int lane = threadIdx.x & 63;
  int hh = lane & 7;
  int es = lane >> 3;
  int h  = es;
  int c  = lane*4;
  float ald_h = ald0[n*8 + hh];
  int beg = offs[n], end = offs[n+1];

  f32x2 A01 = {0.f, 0.f}, A23 = {0.f, 0.f};
  float den = 0.f;

  for(int chunk = beg; chunk < end; chunk += 8){
    int m = end - chunk; if(m > 8) m = 8;
    bool e_ok = es < m;
    int s = e_ok ? csr[chunk + es] : 0;
    float p = 0.f;
    if(e_ok){
      float v = als0[s*8 + hh] + ald_h;
      v = v > 0.f ? v : NEG_SLOPE*v;
      p = expf(v);
    }
    den += p;
    int sj[8]; float pj[8];
    #pragma unroll
    for(int j=0; j<8; j++){
      sj[j] = __shfl(s, j*8);
      pj[j] = __shfl(p, j*8 + h);
    }
    unsigned q[8];
    #pragma unroll
    for(int j=0; j<8; j++)
      q[j] = *(const unsigned*)(h0q + (size_t)sj[j]*256 + c);
    #pragma unroll
    for(int j=0; j<8; j++){
      f32x2 lo, hi, pv;
      dec8x4v(q[j], lo, hi);
      pv[0] = pj[j]; pv[1] = pj[j];
      A01 += pv*lo; A23 += pv*hi;
    }
  }

  den += __shfl_xor(den, 8);
  den += __shfl_xor(den, 16);
  den += __shfl_xor(den, 32);
  float rden = 1.f/(den + 1e-16f);
  rden = __shfl(rden, h);

  float a0 = A01[0]*rden, a1 = A01[1]*rden, a2 = A23[0]*rden, a3 = A23[1]*rden;

  float4 bb = *(const float4*)(b0 + c);
  float4 rb = *(const float4*)(br0 + c);
  uint2 ru = *(const uint2*)(r0b + (size_t)n*256 + c);
  float o0 = a0 + bb.x + __uint_as_float(ru.x << 16)         + rb.x;
  float o1 = a1 + bb.y + __uint_as_float(ru.x & 0xFFFF0000u) + rb.y;
  float o2 = a2 + bb.z + __uint_as_float(ru.y << 16)         + rb.z;
  float o3 = a3 + bb.w + __uint_as_float(ru.y & 0xFFFF0000u) + rb.w;
  ushort4v o;
  o[0] = f2b(o0 > 0.f ? o0 : expf(o0) - 1.f);
  o[1] = f2b(o1 > 0.f ? o1 : expf(o1) - 1.f);
  o[2] = f2b(o2 > 0.f ? o2 : expf(o2) - 1.f);
  o[3] = f2b(o3 > 0.f ? o3 : expf(o3) - 1.f);
  *(ushort4v*)(h1b + (size_t)n*256 + c) = o;
}

// ---- gather layer1: WAVE-per-node over fp8 g1; 4 channels/lane, 4 edge slots ----
__launch_bounds__(256)
extern "C" __global__ void k_gather1(const unsigned short* __restrict__ buf1b,
                                     const unsigned char* __restrict__ g1q,
                                     const float* __restrict__ als1, const float* __restrict__ ald1,
                                     const int* __restrict__ offs, const int* __restrict__ csr,
                                     const float* __restrict__ b1, const float* __restrict__ br1,
                                     float* __restrict__ out, int N){
  int n = blockIdx.x*4 + (threadIdx.x >> 6);
  if(n >= N) return;
  int lane = threadIdx.x & 63;
  int ch4 = lane & 15;
  int es  = lane >> 4;
  int c   = ch4*4;
  int beg = offs[n], end = offs[n+1];
  float ald_n = ald1[n];

  f32x2 A01 = {0.f, 0.f}, A23 = {0.f, 0.f};
  float den = 0.f;

  for(int chunk = beg; chunk < end; chunk += 64){
    int m = end - chunk; if(m > 64) m = 64;
    int s = (lane < m) ? csr[chunk + lane] : 0;
    float p = 0.f;
    if(lane < m){
      float v = als1[s] + ald_n;
      v = v > 0.f ? v : NEG_SLOPE*v;
      p = expf(v);
    }
    den += p;
    for(int base = 0; base < m; base += 16){
      int sv[4]; float pv[4];
      #pragma unroll
      for(int i=0; i<4; i++){
        int j = base + 4*i + es;
        int jj = j & 63;
        sv[i] = __shfl(s, jj);
        pv[i] = __shfl(p, jj);
      }
      unsigned qv[4];
      #pragma unroll
      for(int i=0; i<4; i++)
        qv[i] = *(const unsigned*)(g1q + (size_t)sv[i]*64 + c);
      #pragma unroll
      for(int i=0; i<4; i++){
        f32x2 lo, hi, pp;
        dec8x4v(qv[i], lo, hi);
        pp[0] = pv[i]; pp[1] = pv[i];
        A01 += pp*lo; A23 += pp*hi;
      }
    }
  }

  A01[0] += __shfl_xor(A01[0], 16); A01[1] += __shfl_xor(A01[1], 16);
  A23[0] += __shfl_xor(A23[0], 16); A23[1] += __shfl_xor(A23[1], 16);
  A01[0] += __shfl_xor(A01[0], 32); A01[1] += __shfl_xor(A01[1], 32);
  A23[0] += __shfl_xor(A23[0], 32); A23[1] += __shfl_xor(A23[1], 32);
  #pragma unroll
  for(int o=32; o>0; o>>=1) den += __shfl_xor(den, o);
  float rden = 1.f/(den + 1e-16f);

  float4 bb = *(const float4*)(b1 + c);
  float4 rb = *(const float4*)(br1 + c);
  uint2 ru = *(const uint2*)(buf1b + (size_t)n*128 + 64 + c);
  float v0 = A01[0]*rden + bb.x + __uint_as_float(ru.x << 16)         + rb.x;
  float v1 = A01[1]*rden + bb.y + __uint_as_float(ru.x & 0xFFFF0000u) + rb.y;
  float v2 = A23[0]*rden + bb.z + __uint_as_float(ru.y << 16)         + rb.z;
  float v3 = A23[1]*rden + bb.w + __uint_as_float(ru.y & 0xFFFF0000u) + rb.w;

  float mx = fmaxf(fmaxf(v0, v1), fmaxf(v2, v3));
  #pragma unroll
  for(int o=1; o<16; o<<=1) mx = fmaxf(mx, __shfl_xor(mx, o));
  float sm = expf(v0-mx) + expf(v1-mx) + expf(v2-mx) + expf(v3-mx);
  #pragma unroll
  for(int o=1; o<16; o<<=1) sm += __shfl_xor(sm, o);
  float l = mx + logf(sm);
  if(es == 0){
    float4 ov; ov.x = v0-l; ov.y = v1-l; ov.z = v2-l; ov.w = v3-l;
    *(float4*)(out + (size_t)n*64 + c) = ov;
  }
}

// ---------------- launch ----------------
extern "C" void kernel_launch(void* const* d_in, const int* in_sizes, int n_in,
                              void* d_out, int out_size, void* d_ws, size_t ws_size,
                              hipStream_t stream){
  const float* x   = (const float*)d_in[0];
  const int*   ei  = (const int*)  d_in[1];
  const float* W0  = (const float*)d_in[2];
  const float* as0 = (const float*)d_in[3];
  const float* ad0 = (const float*)d_in[4];
  const float* b0  = (const float*)d_in[5];
  const float* Wr0 = (const float*)d_in[6];
  const float* br0 = (const float*)d_in[7];
  const float* W1  = (const float*)d_in[8];
  const float* as1 = (const float*)d_in[9];
  const float* ad1 = (const float*)d_in[10];
  const float* b1  = (const float*)d_in[11];
  const float* Wr1 = (const float*)d_in[12];
  const float* br1 = (const float*)d_in[13];
  int N = in_sizes[0] / 256;
  int E = in_sizes[1] / 2;
  const int* srcs = ei;
  const int* dsts = ei + E;
  float* out = (float*)d_out;

  int ET = E + N;
  int NBUCK = (N + 127) >> BSH;

  // workspace layout
  unsigned short* r0b   = (unsigned short*)d_ws;        // N*256 bf16 (residual r0)
  unsigned char*  h0q   = (unsigned char*)(r0b + (size_t)N*256);  // N*256 fp8
  unsigned short* h1b   = (unsigned short*)(h0q + (size_t)N*256); // N*256 bf16
  unsigned short* buf1b = h1b + (size_t)N*256;          // N*128 bf16 (g1 | r1)
  unsigned short* WT0   = buf1b + (size_t)N*128;        // 512*256 bf16
  unsigned short* WT1   = WT0   + 512*256;              // 128*256 bf16
  float*    als0 = (float*)(WT1 + 128*256);             // N*8
  float*    ald0 = als0 + (size_t)N*8;                  // N*8
  float*    als1 = ald0 + (size_t)N*8;                  // N
  float*    ald1 = als1 + N;                            // N
  int*      offs = (int*)(ald1 + N);                    // N+1
  int*      bcnt = offs + N + 1;                        // NBUCK
  int*      boffs = bcnt + NBUCK;                       // NBUCK+1
  int*      blockbase = boffs + NBUCK + 1;              // NBLK_PART*NBUCK
  int*      csr  = blockbase + (size_t)NBLK_PART*NBUCK; // ET
  uint2*    pairs = (uint2*)(csr + ET);
  pairs = (uint2*)(((uintptr_t)pairs + 7) & ~(uintptr_t)7);
  unsigned char* g1q = (unsigned char*)(pairs + ET);    // N*64 bytes

  // ---- CSR build: bucket partition ----
  hipMemsetAsync(bcnt, 0, (size_t)NBUCK*sizeof(int), stream);
  hipLaunchKernelGGL(k_part1, dim3(NBLK_PART), dim3(256), 0, stream, dsts, E, N, NBUCK, bcnt, blockbase);
  hipLaunchKernelGGL(k_bscan, dim3(1), dim3(512), 0, stream, bcnt, boffs, offs + N, NBUCK, ET);
  hipLaunchKernelGGL(k_part2, dim3(NBLK_PART), dim3(256), 0, stream, srcs, dsts, E, N, NBUCK, boffs, blockbase, pairs);
  hipLaunchKernelGGL(k_bcsr, dim3(NBUCK), dim3(256), 0, stream, pairs, boffs, N, offs, csr);

  // weight prep
  hipLaunchKernelGGL(k_wt2, dim3((512*256+128*256+255)/256), dim3(256), 0, stream, W0, Wr0, W1, Wr1, WT0, WT1);

  int MB = (N + 127) / 128;
  int g0 = ((MB + 7) / 8) * 32;
  // layer0: x(fp32) @ [W0|Wr0] -> fp8 h0q + bf16 r0b + fused als0/ald0
  hipLaunchKernelGGL(k_mgemm, dim3(g0), dim3(256), 0, stream,
                     (const unsigned short*)nullptr, x, WT0,
                     (unsigned short*)nullptr, N, MB, 4, 0,
                     h0q, r0b, as0, ad0, als0, ald0);
  hipLaunchKernelGGL(k_gather0, dim3((N+3)/4), dim3(256), 0, stream, r0b, h0q, als0, ald0, offs, csr, b0, br0, h1b, N);

  // layer1: h1b @ [W1|Wr1] -> bf16 buf1b + fp8 g1q + fused als1/ald1
  hipLaunchKernelGGL(k_mgemm, dim3(MB), dim3(256), 0, stream,
                     h1b, (const float*)nullptr, WT1,
                     buf1b, N, MB, 1, 1,
                     g1q, (unsigned short*)nullptr,
                     as1, ad1, als1, ald1);
  hipLaunchKernelGGL(k_gather1, dim3((N+3)/4), dim3(256), 0, stream, buf1b, g1q, als1, ald1, offs, csr, b1, br1, out, N);
}

// Round 21
// 181.030 us; speedup vs baseline: 1.0876x; 1.0876x over previous
//
#include <hip/hip_runtime.h>
#include <math.h>

#define NEG_SLOPE 0.2f
#define BSH 7              // 128 nodes per bucket
#define NBLK_PART 256      // partition blocks

typedef __attribute__((ext_vector_type(8))) short bf16x8;
typedef __attribute__((ext_vector_type(4))) float f32x4;
typedef __attribute__((ext_vector_type(2))) float f32x2;
typedef __attribute__((ext_vector_type(8))) unsigned short ushort8;
typedef __attribute__((ext_vector_type(4))) unsigned short ushort4v;

__device__ __forceinline__ float b2f(unsigned short u){
  return __uint_as_float(((unsigned)u) << 16);
}
__device__ __forceinline__ unsigned short f2b(float f){
  unsigned u = __float_as_uint(f);
  return (unsigned short)((u + 0x7FFFu + ((u >> 16) & 1u)) >> 16);
}

// ---- fp8 e4m3fn helpers (hardware cvt if available, bit-twiddle fallback) ----
#if __has_builtin(__builtin_amdgcn_cvt_pk_f32_fp8) && __has_builtin(__builtin_amdgcn_cvt_pk_fp8_f32)
#define HW_FP8 1
#else
#define HW_FP8 0
#endif

#if !HW_FP8
__device__ __forceinline__ unsigned enc8_one(float f){
  unsigned bits = __float_as_uint(f);
  unsigned s = bits >> 31;
  unsigned e = (bits >> 23) & 255;
  unsigned mant = bits & 0x7FFFFF;
  if(e < 121){
    float af = fabsf(f);
    int m = (int)(af * 512.f + 0.5f);
    if(m > 7) m = 7;
    return (s << 7) | (unsigned)m;
  }
  unsigned lsb = (mant >> 20) & 1;
  mant += 0x7FFFF + lsb;
  if(mant >> 23){ e += 1; mant = 0; }
  unsigned m3 = mant >> 20;
  unsigned e8 = e - 120;
  if(e8 > 15 || (e8 == 15 && m3 == 7)) return (s << 7) | 0x7E;
  return (s << 7) | (e8 << 3) | m3;
}
#endif

template<bool HI>
__device__ __forceinline__ unsigned enc8_pair(float a, float b, unsigned old){
#if HW_FP8
  return __builtin_amdgcn_cvt_pk_fp8_f32(a, b, old, HI);  // HI literal (op_sel)
#else
  unsigned p = enc8_one(a) | (enc8_one(b) << 8);
  return HI ? ((old & 0x0000FFFFu) | (p << 16)) : ((old & 0xFFFF0000u) | p);
#endif
}

__device__ __forceinline__ void dec8x4v(unsigned q, f32x2& lo, f32x2& hi){
#if HW_FP8
  lo = __builtin_amdgcn_cvt_pk_f32_fp8(q, false);
  hi = __builtin_amdgcn_cvt_pk_f32_fp8(q, true);
#else
  auto dec1 = [](unsigned b)->float{
    unsigned s = (b >> 7) & 1, e = (b >> 3) & 15, m = b & 7;
    float v = (e == 0) ? (float)m * 0.001953125f
                       : __uint_as_float(((e + 120) << 23) | (m << 20));
    return s ? -v : v;
  };
  lo[0] = dec1(q & 255); lo[1] = dec1((q >> 8) & 255);
  hi[0] = dec1((q >> 16) & 255); hi[1] = dec1(q >> 24);
#endif
}

// ================= bucket-partitioned CSR build =================
extern "C" __global__ void k_part1(const int* __restrict__ dsts, int E, int N,
                                   int NBUCK, int* __restrict__ bcnt,
                                   int* __restrict__ blockbase){
  __shared__ int hist[512];
  int blk = blockIdx.x, tid = threadIdx.x;
  for(int b = tid; b < NBUCK; b += 256) hist[b] = 0;
  __syncthreads();
  int ET = E + N;
  int chunk = (ET + NBLK_PART - 1)/NBLK_PART;
  int s0 = blk*chunk, s1 = s0+chunk < ET ? s0+chunk : ET;
  for(int e = s0+tid; e < s1; e += 256){
    int d = (e < E) ? dsts[e] : e - E;
    atomicAdd(&hist[d >> BSH], 1);
  }
  __syncthreads();
  for(int b = tid; b < NBUCK; b += 256)
    blockbase[(size_t)blk*NBUCK + b] = atomicAdd(&bcnt[b], hist[b]);
}

extern "C" __global__ void k_bscan(const int* __restrict__ bcnt, int* __restrict__ boffs,
                                   int* __restrict__ offs_last, int NBUCK, int ET){
  __shared__ int sc[512], orig[512];
  int t = threadIdx.x;
  int v = (t < NBUCK) ? bcnt[t] : 0;
  sc[t] = v; orig[t] = v;
  __syncthreads();
  for(int st=1; st<512; st<<=1){
    int u = (t >= st) ? sc[t-st] : 0;
    __syncthreads();
    sc[t] += u;
    __syncthreads();
  }
  if(t < NBUCK) boffs[t] = sc[t] - orig[t];
  if(t == 0){ boffs[NBUCK] = ET; *offs_last = ET; }
}

extern "C" __global__ void k_part2(const int* __restrict__ srcs, const int* __restrict__ dsts,
                                   int E, int N, int NBUCK,
                                   const int* __restrict__ boffs, const int* __restrict__ blockbase,
                                   uint2* __restrict__ pairs){
  __shared__ int cur[512];
  int blk = blockIdx.x, tid = threadIdx.x;
  for(int b = tid; b < NBUCK; b += 256)
    cur[b] = boffs[b] + blockbase[(size_t)blk*NBUCK + b];
  __syncthreads();
  int ET = E + N;
  int chunk = (ET + NBLK_PART - 1)/NBLK_PART;
  int s0 = blk*chunk, s1 = s0+chunk < ET ? s0+chunk : ET;
  for(int e = s0+tid; e < s1; e += 256){
    int s, d;
    if(e < E){ s = srcs[e]; d = dsts[e]; } else { s = d = e - E; }
    int pos = atomicAdd(&cur[d >> BSH], 1);
    uint2 pr; pr.x = (unsigned)d; pr.y = (unsigned)s;
    pairs[pos] = pr;
  }
}

extern "C" __global__ void k_bcsr(const uint2* __restrict__ pairs, const int* __restrict__ boffs,
                                  int N, int* __restrict__ offs, int* __restrict__ csr){
  __shared__ int hist[128], sc[128], lcur[128];
  int b = blockIdx.x, tid = threadIdx.x;
  int node0 = b << BSH;
  int base = boffs[b], endp = boffs[b+1];
  if(tid < 128) hist[tid] = 0;
  __syncthreads();
  for(int i = base + tid; i < endp; i += 256)
    atomicAdd(&hist[pairs[i].x & 127], 1);
  __syncthreads();
  if(tid < 128) sc[tid] = hist[tid];
  __syncthreads();
  for(int st=1; st<128; st<<=1){
    int u = (tid < 128 && tid >= st) ? sc[tid-st] : 0;
    __syncthreads();
    if(tid < 128) sc[tid] += u;
    __syncthreads();
  }
  if(tid < 128){
    int ex = sc[tid] - hist[tid];
    lcur[tid] = ex;
    int n = node0 + tid;
    if(n < N) offs[n] = base + ex;
  }
  __syncthreads();
  for(int i = base + tid; i < endp; i += 256){
    uint2 pr = pairs[i];
    int pos = atomicAdd(&lcur[pr.x & 127], 1);
    csr[base + pos] = (int)pr.y;
  }
}

// ---------------- weight transpose+concat (both layers, one launch) ----------------
extern "C" __global__ void k_wt2(const float* __restrict__ W0, const float* __restrict__ Wr0,
                                 const float* __restrict__ W1, const float* __restrict__ Wr1,
                                 unsigned short* __restrict__ WT0, unsigned short* __restrict__ WT1){
  int idx = blockIdx.x*256 + threadIdx.x;
  const int tot0 = 512*256;
  if(idx < tot0){
    int n = idx >> 8, k = idx & 255;
    const float* W = (n < 256) ? W0 : Wr0;
    int c = (n < 256) ? n : n - 256;
    WT0[idx] = f2b(W[(size_t)k*256 + c]);
  } else {
    idx -= tot0;
    if(idx >= 128*256) return;
    int n = idx >> 8, k = idx & 255;
    const float* W = (n < 64) ? W1 : Wr1;
    int c = (n < 64) ? n : n - 64;
    WT1[idx] = f2b(W[(size_t)k*64 + c]);
  }
}

// ---------------- bf16 MFMA GEMM (R19 staging) + conflict-free half-tile epilogue ----------------
// A: fp32 pipelined reg-stage (layer0) or bf16 global_load_lds (layer1); B: global_load_lds.
// Epilogue: 2 half-tiles of 64 rows through LDS at stride 136 (bank-skewed, 16B aligned).
// mode 0 (layer0): col_blk 0,1 -> fp8 h0q + fused als/ald; col_blk 2,3 -> bf16 r0b.
// mode 1 (layer1): bf16 C (ldc=128) + fp8 g1q (cols<64) + fused als1/ald1.
__launch_bounds__(256)
extern "C" __global__ void k_mgemm(const unsigned short* __restrict__ Ab,
                                   const float* __restrict__ Afp,
                                   const unsigned short* __restrict__ WT,
                                   unsigned short* __restrict__ C, int M,
                                   int MB, int NCB, int mode,
                                   unsigned char* __restrict__ qout,
                                   unsigned short* __restrict__ rout,
                                   const float* __restrict__ asv, const float* __restrict__ adv,
                                   float* __restrict__ alsout, float* __restrict__ aldout){
  int id = blockIdx.x;
  int row_blk, col_blk;
  if(NCB == 4){
    col_blk = (id >> 3) & 3;
    row_blk = (id >> 5)*8 + (id & 7);
  } else {
    row_blk = id; col_blk = 0;
  }
  if(row_blk >= MB) return;

  __shared__ unsigned short SH[128*128];   // As|Bs (32768B); epilogue CT (64x136)
  unsigned short* As = SH;
  unsigned short* Bs = SH + 128*64;
  int t = threadIdx.x;
  int lane = t & 63, wid = t >> 6;
  int wr = wid >> 1, wc = wid & 1;
  int row0 = row_blk*128, col0 = col_blk*128;
  f32x4 acc[4][4] = {};

  // fp32 A path: pipelined reg staging (issue-early / write-late)
  float4 v0s[4], v1s[4];
  const float* abase[4];
  if(Afp){
    #pragma unroll
    for(int i=0; i<4; i++){
      int t2 = i*256 + t;
      int r = t2 >> 3;
      int dslot = (t2 & 7) ^ (r & 7);
      int gr = row0 + r; if(gr >= M) gr = M - 1;
      abase[i] = Afp + (size_t)gr*256 + dslot*8;
      v0s[i] = *(const float4*)(abase[i]);
      v1s[i] = *(const float4*)(abase[i] + 4);
    }
  }

  for(int k0 = 0; k0 < 256; k0 += 64){
    if(Afp){
      #pragma unroll
      for(int i=0; i<4; i++){
        ushort8 o;
        o[0]=f2b(v0s[i].x); o[1]=f2b(v0s[i].y); o[2]=f2b(v0s[i].z); o[3]=f2b(v0s[i].w);
        o[4]=f2b(v1s[i].x); o[5]=f2b(v1s[i].y); o[6]=f2b(v1s[i].z); o[7]=f2b(v1s[i].w);
        *(ushort8*)(As + i*2048 + wid*512 + lane*8) = o;
      }
    } else {
      #pragma unroll
      for(int i=0; i<4; i++){
        int t2 = i*256 + t;
        int r = t2 >> 3;
        int dslot = (t2 & 7) ^ (r & 7);
        int gr = row0 + r; if(gr >= M) gr = M - 1;
        const unsigned short* ga = Ab + (size_t)gr*256 + k0 + dslot*8;
        __builtin_amdgcn_global_load_lds((const __attribute__((address_space(1))) unsigned*)ga,
            (__attribute__((address_space(3))) unsigned*)(As + i*2048 + wid*512), 16, 0, 0);
      }
    }
    #pragma unroll
    for(int i=0; i<4; i++){
      int t2 = i*256 + t;
      int r = t2 >> 3;
      int dslot = (t2 & 7) ^ (r & 7);
      const unsigned short* gb = WT + (size_t)(col0 + r)*256 + k0 + dslot*8;
      __builtin_amdgcn_global_load_lds((const __attribute__((address_space(1))) unsigned*)gb,
          (__attribute__((address_space(3))) unsigned*)(Bs + i*2048 + wid*512), 16, 0, 0);
    }
    __syncthreads();
    if(Afp && k0 < 192){
      #pragma unroll
      for(int i=0; i<4; i++){
        v0s[i] = *(const float4*)(abase[i] + k0 + 64);
        v1s[i] = *(const float4*)(abase[i] + k0 + 68);
      }
    }
    #pragma unroll
    for(int kc=0; kc<2; kc++){
      bf16x8 a[4], b[4];
      int kb = kc*4 + (lane >> 4);
      #pragma unroll
      for(int f=0; f<4; f++){
        int ar = wr*64 + f*16 + (lane & 15);
        a[f] = *(const bf16x8*)&As[ar*64 + ((kb ^ (ar & 7))*8)];
        int br = wc*64 + f*16 + (lane & 15);
        b[f] = *(const bf16x8*)&Bs[br*64 + ((kb ^ (br & 7))*8)];
      }
      #pragma unroll
      for(int fm=0; fm<4; fm++)
        #pragma unroll
        for(int fn=0; fn<4; fn++)
          acc[fm][fn] = __builtin_amdgcn_mfma_f32_16x16x32_bf16(a[fm], b[fn], acc[fm][fn], 0, 0, 0);
    }
    __syncthreads();
  }

  // ---- epilogue: 2 half-tiles of 64 rows through LDS (stride 136), coalesced output ----
  unsigned short* CT = SH;
  int cg = t & 15;
  #pragma unroll
  for(int half=0; half<2; half++){
    __syncthreads();
    if(wr == half){
      #pragma unroll
      for(int fm=0; fm<4; fm++){
        int rbase = fm*16 + ((lane>>4)<<2);
        #pragma unroll
        for(int r=0; r<4; r++)
          #pragma unroll
          for(int fn=0; fn<4; fn++)
            CT[(rbase+r)*136 + wc*64 + (lane&15) + fn*16] = f2b(acc[fm][fn][r]);
      }
    }
    __syncthreads();
    if(mode == 0){
      bool attn = col_blk < 2;
      int colbase = col0 + cg*8;
      float4 as_lo, as_hi, ad_lo, ad_hi;
      if(attn){
        as_lo = *(const float4*)(asv + colbase);
        as_hi = *(const float4*)(asv + colbase + 4);
        ad_lo = *(const float4*)(adv + colbase);
        ad_hi = *(const float4*)(adv + colbase + 4);
      }
      #pragma unroll
      for(int it=0; it<4; it++){
        int rl = it*16 + (t>>4);
        int row = row0 + half*64 + rl;
        ushort8 vr = *(ushort8*)&CT[rl*136 + cg*8];
        if(attn){
          float f0=b2f(vr[0]),f1=b2f(vr[1]),f2=b2f(vr[2]),f3=b2f(vr[3]);
          float f4=b2f(vr[4]),f5=b2f(vr[5]),f6=b2f(vr[6]),f7=b2f(vr[7]);
          float sd = f0*as_lo.x+f1*as_lo.y+f2*as_lo.z+f3*as_lo.w
                   + f4*as_hi.x+f5*as_hi.y+f6*as_hi.z+f7*as_hi.w;
          float dd = f0*ad_lo.x+f1*ad_lo.y+f2*ad_lo.z+f3*ad_lo.w
                   + f4*ad_hi.x+f5*ad_hi.y+f6*ad_hi.z+f7*ad_hi.w;
          sd += __shfl_xor(sd,1); sd += __shfl_xor(sd,2);   // 4 lanes = 32 cols = 1 head
          dd += __shfl_xor(dd,1); dd += __shfl_xor(dd,2);
          uint2 q;
          q.x = enc8_pair<false>(f0,f1,0u); q.x = enc8_pair<true>(f2,f3,q.x);
          q.y = enc8_pair<false>(f4,f5,0u); q.y = enc8_pair<true>(f6,f7,q.y);
          if(row < M){
            *(uint2*)(qout + (size_t)row*256 + colbase) = q;
            if((t&3)==0){
              int head = colbase >> 5;
              alsout[row*8 + head] = sd;
              aldout[row*8 + head] = dd;
            }
          }
        } else {
          if(row < M)
            *(ushort8*)(rout + (size_t)row*256 + (colbase - 256)) = vr;
        }
      }
    } else {
      #pragma unroll
      for(int it=0; it<4; it++){
        int rl = it*16 + (t>>4);
        int row = row0 + half*64 + rl;
        ushort8 vr = *(ushort8*)&CT[rl*136 + cg*8];
        if(row < M){
          *(ushort8*)(C + (size_t)row*128 + cg*8) = vr;
          if(cg < 8){
            float f0=b2f(vr[0]),f1=b2f(vr[1]),f2=b2f(vr[2]),f3=b2f(vr[3]);
            float f4=b2f(vr[4]),f5=b2f(vr[5]),f6=b2f(vr[6]),f7=b2f(vr[7]);
            uint2 q;
            q.x = enc8_pair<false>(f0,f1,0u); q.x = enc8_pair<true>(f2,f3,q.x);
            q.y = enc8_pair<false>(f4,f5,0u); q.y = enc8_pair<true>(f6,f7,q.y);
            *(uint2*)(qout + (size_t)row*64 + cg*8) = q;
            // fused layer1 logits: dot over 64 g1 cols (8 per lane, reduce over cg 0..7)
            float sd = f0*asv[cg*8+0]+f1*asv[cg*8+1]+f2*asv[cg*8+2]+f3*asv[cg*8+3]
                     + f4*asv[cg*8+4]+f5*asv[cg*8+5]+f6*asv[cg*8+6]+f7*asv[cg*8+7];
            float dd = f0*adv[cg*8+0]+f1*adv[cg*8+1]+f2*adv[cg*8+2]+f3*adv[cg*8+3]
                     + f4*adv[cg*8+4]+f5*adv[cg*8+5]+f6*adv[cg*8+6]+f7*adv[cg*8+7];
            sd += __shfl_xor(sd,1); sd += __shfl_xor(sd,2); sd += __shfl_xor(sd,4);
            dd += __shfl_xor(dd,1); dd += __shfl_xor(dd,2); dd += __shfl_xor(dd,4);
            if((t&15)==0){
              alsout[row] = sd;
              aldout[row] = dd;
            }
          }
        }
      }
    }
  }
}

// ---- gather layer0: WAVE-per-node, zero LDS / zero barriers ----
__launch_bounds__(256)
extern "C" __global__ void k_gather0(const unsigned short* __restrict__ r0b,
                                     const unsigned char* __restrict__ h0q,
                                     const float* __restrict__ als0, const float* __restrict__ ald0,
                                     const int* __restrict__ offs, const int* __restrict__ csr,
                                     const float* __restrict__ b0, const float* __restrict__ br0,
                                     unsigned short* __restrict__ h1b, int N){
  int n = blockIdx.x*4 + (threadIdx.x >> 6);
  if(n >= N) return;
  int lane = threadIdx.x & 63;
  int hh = lane & 7;
  int es = lane >> 3;
  int h  = es;
  int c  = lane*4;
  float ald_h = ald0[n*8 + hh];
  int beg = offs[n], end = offs[n+1];

  f32x2 A01 = {0.f, 0.f}, A23 = {0.f, 0.f};
  float den = 0.f;

  for(int chunk = beg; chunk < end; chunk += 8){
    int m = end - chunk; if(m > 8) m = 8;
    bool e_ok = es < m;
    int s = e_ok ? csr[chunk + es] : 0;
    float p = 0.f;
    if(e_ok){
      float v = als0[s*8 + hh] + ald_h;
      v = v > 0.f ? v : NEG_SLOPE*v;
      p = expf(v);
    }
    den += p;
    int sj[8]; float pj[8];
    #pragma unroll
    for(int j=0; j<8; j++){
      sj[j] = __shfl(s, j*8);
      pj[j] = __shfl(p, j*8 + h);
    }
    unsigned q[8];
    #pragma unroll
    for(int j=0; j<8; j++)
      q[j] = *(const unsigned*)(h0q + (size_t)sj[j]*256 + c);
    #pragma unroll
    for(int j=0; j<8; j++){
      f32x2 lo, hi, pv;
      dec8x4v(q[j], lo, hi);
      pv[0] = pj[j]; pv[1] = pj[j];
      A01 += pv*lo; A23 += pv*hi;
    }
  }

  den += __shfl_xor(den, 8);
  den += __shfl_xor(den, 16);
  den += __shfl_xor(den, 32);
  float rden = 1.f/(den + 1e-16f);
  rden = __shfl(rden, h);

  float a0 = A01[0]*rden, a1 = A01[1]*rden, a2 = A23[0]*rden, a3 = A23[1]*rden;

  float4 bb = *(const float4*)(b0 + c);
  float4 rb = *(const float4*)(br0 + c);
  uint2 ru = *(const uint2*)(r0b + (size_t)n*256 + c);
  float o0 = a0 + bb.x + __uint_as_float(ru.x << 16)         + rb.x;
  float o1 = a1 + bb.y + __uint_as_float(ru.x & 0xFFFF0000u) + rb.y;
  float o2 = a2 + bb.z + __uint_as_float(ru.y << 16)         + rb.z;
  float o3 = a3 + bb.w + __uint_as_float(ru.y & 0xFFFF0000u) + rb.w;
  ushort4v o;
  o[0] = f2b(o0 > 0.f ? o0 : expf(o0) - 1.f);
  o[1] = f2b(o1 > 0.f ? o1 : expf(o1) - 1.f);
  o[2] = f2b(o2 > 0.f ? o2 : expf(o2) - 1.f);
  o[3] = f2b(o3 > 0.f ? o3 : expf(o3) - 1.f);
  *(ushort4v*)(h1b + (size_t)n*256 + c) = o;
}

// ---- gather layer1: WAVE-per-node over fp8 g1; 4 channels/lane, 4 edge slots ----
__launch_bounds__(256)
extern "C" __global__ void k_gather1(const unsigned short* __restrict__ buf1b,
                                     const unsigned char* __restrict__ g1q,
                                     const float* __restrict__ als1, const float* __restrict__ ald1,
                                     const int* __restrict__ offs, const int* __restrict__ csr,
                                     const float* __restrict__ b1, const float* __restrict__ br1,
                                     float* __restrict__ out, int N){
  int n = blockIdx.x*4 + (threadIdx.x >> 6);
  if(n >= N) return;
  int lane = threadIdx.x & 63;
  int ch4 = lane & 15;
  int es  = lane >> 4;
  int c   = ch4*4;
  int beg = offs[n], end = offs[n+1];
  float ald_n = ald1[n];

  f32x2 A01 = {0.f, 0.f}, A23 = {0.f, 0.f};
  float den = 0.f;

  for(int chunk = beg; chunk < end; chunk += 64){
    int m = end - chunk; if(m > 64) m = 64;
    int s = (lane < m) ? csr[chunk + lane] : 0;
    float p = 0.f;
    if(lane < m){
      float v = als1[s] + ald_n;
      v = v > 0.f ? v : NEG_SLOPE*v;
      p = expf(v);
    }
    den += p;
    for(int base = 0; base < m; base += 16){
      int sv[4]; float pv[4];
      #pragma unroll
      for(int i=0; i<4; i++){
        int j = base + 4*i + es;
        int jj = j & 63;
        sv[i] = __shfl(s, jj);
        pv[i] = __shfl(p, jj);
      }
      unsigned qv[4];
      #pragma unroll
      for(int i=0; i<4; i++)
        qv[i] = *(const unsigned*)(g1q + (size_t)sv[i]*64 + c);
      #pragma unroll
      for(int i=0; i<4; i++){
        f32x2 lo, hi, pp;
        dec8x4v(qv[i], lo, hi);
        pp[0] = pv[i]; pp[1] = pv[i];
        A01 += pp*lo; A23 += pp*hi;
      }
    }
  }

  A01[0] += __shfl_xor(A01[0], 16); A01[1] += __shfl_xor(A01[1], 16);
  A23[0] += __shfl_xor(A23[0], 16); A23[1] += __shfl_xor(A23[1], 16);
  A01[0] += __shfl_xor(A01[0], 32); A01[1] += __shfl_xor(A01[1], 32);
  A23[0] += __shfl_xor(A23[0], 32); A23[1] += __shfl_xor(A23[1], 32);
  #pragma unroll
  for(int o=32; o>0; o>>=1) den += __shfl_xor(den, o);
  float rden = 1.f/(den + 1e-16f);

  float4 bb = *(const float4*)(b1 + c);
  float4 rb = *(const float4*)(br1 + c);
  uint2 ru = *(const uint2*)(buf1b + (size_t)n*128 + 64 + c);
  float v0 = A01[0]*rden + bb.x + __uint_as_float(ru.x << 16)         + rb.x;
  float v1 = A01[1]*rden + bb.y + __uint_as_float(ru.x & 0xFFFF0000u) + rb.y;
  float v2 = A23[0]*rden + bb.z + __uint_as_float(ru.y << 16)         + rb.z;
  float v3 = A23[1]*rden + bb.w + __uint_as_float(ru.y & 0xFFFF0000u) + rb.w;

  float mx = fmaxf(fmaxf(v0, v1), fmaxf(v2, v3));
  #pragma unroll
  for(int o=1; o<16; o<<=1) mx = fmaxf(mx, __shfl_xor(mx, o));
  float sm = expf(v0-mx) + expf(v1-mx) + expf(v2-mx) + expf(v3-mx);
  #pragma unroll
  for(int o=1; o<16; o<<=1) sm += __shfl_xor(sm, o);
  float l = mx + logf(sm);
  if(es == 0){
    float4 ov; ov.x = v0-l; ov.y = v1-l; ov.z = v2-l; ov.w = v3-l;
    *(float4*)(out + (size_t)n*64 + c) = ov;
  }
}

// ---------------- launch ----------------
extern "C" void kernel_launch(void* const* d_in, const int* in_sizes, int n_in,
                              void* d_out, int out_size, void* d_ws, size_t ws_size,
                              hipStream_t stream){
  const float* x   = (const float*)d_in[0];
  const int*   ei  = (const int*)  d_in[1];
  const float* W0  = (const float*)d_in[2];
  const float* as0 = (const float*)d_in[3];
  const float* ad0 = (const float*)d_in[4];
  const float* b0  = (const float*)d_in[5];
  const float* Wr0 = (const float*)d_in[6];
  const float* br0 = (const float*)d_in[7];
  const float* W1  = (const float*)d_in[8];
  const float* as1 = (const float*)d_in[9];
  const float* ad1 = (const float*)d_in[10];
  const float* b1  = (const float*)d_in[11];
  const float* Wr1 = (const float*)d_in[12];
  const float* br1 = (const float*)d_in[13];
  int N = in_sizes[0] / 256;
  int E = in_sizes[1] / 2;
  const int* srcs = ei;
  const int* dsts = ei + E;
  float* out = (float*)d_out;

  int ET = E + N;
  int NBUCK = (N + 127) >> BSH;

  // workspace layout
  unsigned short* r0b   = (unsigned short*)d_ws;        // N*256 bf16 (residual r0)
  unsigned char*  h0q   = (unsigned char*)(r0b + (size_t)N*256);  // N*256 fp8
  unsigned short* h1b   = (unsigned short*)(h0q + (size_t)N*256); // N*256 bf16
  unsigned short* buf1b = h1b + (size_t)N*256;          // N*128 bf16 (g1 | r1)
  unsigned short* WT0   = buf1b + (size_t)N*128;        // 512*256 bf16
  unsigned short* WT1   = WT0   + 512*256;              // 128*256 bf16
  float*    als0 = (float*)(WT1 + 128*256);             // N*8
  float*    ald0 = als0 + (size_t)N*8;                  // N*8
  float*    als1 = ald0 + (size_t)N*8;                  // N
  float*    ald1 = als1 + N;                            // N
  int*      offs = (int*)(ald1 + N);                    // N+1
  int*      bcnt = offs + N + 1;                        // NBUCK
  int*      boffs = bcnt + NBUCK;                       // NBUCK+1
  int*      blockbase = boffs + NBUCK + 1;              // NBLK_PART*NBUCK
  int*      csr  = blockbase + (size_t)NBLK_PART*NBUCK; // ET
  uint2*    pairs = (uint2*)(csr + ET);
  pairs = (uint2*)(((uintptr_t)pairs + 7) & ~(uintptr_t)7);
  unsigned char* g1q = (unsigned char*)(pairs + ET);    // N*64 bytes

  // ---- CSR build: bucket partition ----
  hipMemsetAsync(bcnt, 0, (size_t)NBUCK*sizeof(int), stream);
  hipLaunchKernelGGL(k_part1, dim3(NBLK_PART), dim3(256), 0, stream, dsts, E, N, NBUCK, bcnt, blockbase);
  hipLaunchKernelGGL(k_bscan, dim3(1), dim3(512), 0, stream, bcnt, boffs, offs + N, NBUCK, ET);
  hipLaunchKernelGGL(k_part2, dim3(NBLK_PART), dim3(256), 0, stream, srcs, dsts, E, N, NBUCK, boffs, blockbase, pairs);
  hipLaunchKernelGGL(k_bcsr, dim3(NBUCK), dim3(256), 0, stream, pairs, boffs, N, offs, csr);

  // weight prep
  hipLaunchKernelGGL(k_wt2, dim3((512*256+128*256+255)/256), dim3(256), 0, stream, W0, Wr0, W1, Wr1, WT0, WT1);

  int MB = (N + 127) / 128;
  int g0 = ((MB + 7) / 8) * 32;
  // layer0: x(fp32) @ [W0|Wr0] -> fp8 h0q + bf16 r0b + fused als0/ald0
  hipLaunchKernelGGL(k_mgemm, dim3(g0), dim3(256), 0, stream,
                     (const unsigned short*)nullptr, x, WT0,
                     (unsigned short*)nullptr, N, MB, 4, 0,
                     h0q, r0b, as0, ad0, als0, ald0);
  hipLaunchKernelGGL(k_gather0, dim3((N+3)/4), dim3(256), 0, stream, r0b, h0q, als0, ald0, offs, csr, b0, br0, h1b, N);

  // layer1: h1b @ [W1|Wr1] -> bf16 buf1b + fp8 g1q + fused als1/ald1
  hipLaunchKernelGGL(k_mgemm, dim3(MB), dim3(256), 0, stream,
                     h1b, (const float*)nullptr, WT1,
                     buf1b, N, MB, 1, 1,
                     g1q, (unsigned short*)nullptr,
                     as1, ad1, als1, ald1);
  hipLaunchKernelGGL(k_gather1, dim3((N+3)/4), dim3(256), 0, stream, buf1b, g1q, als1, ald1, offs, csr, b1, br1, out, N);
}